// Round 1
// baseline (589.566 us; speedup 1.0000x reference)
//
#include <hip/hip_runtime.h>

// PhaseCoherenceLoss: scalar reduction over (B, T, 3) fp32 logits.
// For each pair (t, t+1): pt=argmax[t], pt1=argmax[t+1]; if illegal[pt][pt1],
// accumulate (logit[t+1, pt1])^2 (== max logit at t+1) and count.
// out = count>0 ? 10*loss/count : 0.
//
// Illegal transitions (pt,pt1): (0,2),(1,0),(2,0),(2,1)
// -> bit index pt*3+pt1 in {2,3,6,7} -> mask 0xCC.

__global__ __launch_bounds__(256) void pcl_main(const float* __restrict__ x,
                                                double* __restrict__ ws_loss,
                                                unsigned int* __restrict__ ws_count,
                                                int B, int T) {
    const unsigned int tpr = (unsigned int)(T >> 2);   // threads per row (T/4)
    unsigned long long gid = (unsigned long long)blockIdx.x * blockDim.x + threadIdx.x;
    unsigned long long total = (unsigned long long)B * tpr;

    float loss = 0.0f;
    unsigned int cnt = 0;

    if (gid < total) {
        unsigned int row = (unsigned int)(gid / tpr);
        unsigned int s4  = (unsigned int)(gid % tpr);
        int t0 = (int)(s4 << 2);
        const float4* p = (const float4*)(x + ((long long)row * T + t0) * 3);

        float4 f0 = p[0];
        float4 f1 = p[1];
        float4 f2 = p[2];
        bool last = (t0 + 4 >= T);                     // last chunk in row: no successor tile
        float4 f3;
        if (!last) f3 = p[3]; else f3 = make_float4(0.f, 0.f, 0.f, 0.f);

        // 5 timesteps' logit triples (t0..t0+4), all compile-time indexed
        float v[5][3] = {
            {f0.x, f0.y, f0.z},
            {f0.w, f1.x, f1.y},
            {f1.z, f1.w, f2.x},
            {f2.y, f2.z, f2.w},
            {f3.x, f3.y, f3.z}
        };

        int   idx[5];
        float mx[5];
        #pragma unroll
        for (int k = 0; k < 5; ++k) {
            float b0 = v[k][0]; int bi = 0;
            if (v[k][1] > b0) { b0 = v[k][1]; bi = 1; }   // strict > keeps first-max (argmax tie-break)
            if (v[k][2] > b0) { b0 = v[k][2]; bi = 2; }
            idx[k] = bi; mx[k] = b0;
        }

        int npairs = last ? 3 : 4;
        #pragma unroll
        for (int k = 0; k < 4; ++k) {
            if (k < npairs) {
                int code = idx[k] * 3 + idx[k + 1];
                if ((0xCC >> code) & 1) {
                    loss += mx[k + 1] * mx[k + 1];
                    cnt  += 1u;
                }
            }
        }
    }

    // wave-64 butterfly-free down-reduce
    #pragma unroll
    for (int off = 32; off > 0; off >>= 1) {
        loss += __shfl_down(loss, off, 64);
        cnt  += __shfl_down(cnt,  off, 64);
    }

    __shared__ float        sl[4];
    __shared__ unsigned int sc[4];
    int lane = threadIdx.x & 63;
    int wid  = threadIdx.x >> 6;
    if (lane == 0) { sl[wid] = loss; sc[wid] = cnt; }
    __syncthreads();

    if (threadIdx.x == 0) {
        float        L = sl[0] + sl[1] + sl[2] + sl[3];
        unsigned int C = sc[0] + sc[1] + sc[2] + sc[3];
        atomicAdd(ws_loss, (double)L);
        atomicAdd(ws_count, C);
    }
}

__global__ void pcl_final(const double* __restrict__ ws_loss,
                          const unsigned int* __restrict__ ws_count,
                          float* __restrict__ out) {
    double L = *ws_loss;
    unsigned int C = *ws_count;
    out[0] = (C > 0u) ? (float)(10.0 * L / (double)C) : 0.0f;
}

extern "C" void kernel_launch(void* const* d_in, const int* in_sizes, int n_in,
                              void* d_out, int out_size, void* d_ws, size_t ws_size,
                              hipStream_t stream) {
    const float* x = (const float*)d_in[0];
    const int C = 3;
    const int T = 8192;
    const int B = in_sizes[0] / (C * T);

    double*       ws_loss  = (double*)d_ws;
    unsigned int* ws_count = (unsigned int*)((char*)d_ws + 8);

    // ws is re-poisoned to 0xAA before every timed launch — zero it on-stream.
    hipMemsetAsync(d_ws, 0, 16, stream);

    unsigned long long total = (unsigned long long)B * (unsigned long long)(T / 4);
    int block = 256;
    unsigned int grid = (unsigned int)((total + block - 1) / block);

    pcl_main<<<grid, block, 0, stream>>>(x, ws_loss, ws_count, B, T);
    pcl_final<<<1, 1, 0, stream>>>(ws_loss, ws_count, (float*)d_out);
}

// Round 3
// 271.406 us; speedup vs baseline: 2.1723x; 2.1723x over previous
//
#include <hip/hip_runtime.h>

// PhaseCoherenceLoss: scalar reduction over (B, T=8192, 3) fp32 logits.
// For pair (t,t+1): pt=argmax[t], pt1=argmax[t+1]; if illegal[pt][pt1],
// accumulate (max logit at t+1)^2 and count. out = count>0 ? 10*loss/count : 0.
// Illegal codes pt*3+pt1 in {2,3,6,7} -> bitmask 0xCC.
//
// Stage 1: 2048 blocks x 256 threads, grid-stride (8 chunks of 4 timesteps per
//          thread), per-block partial -> d_ws (NO global atomics: R1 showed
//          16K same-address atomics serialized the whole kernel, 392us @ 3% BW).
// Stage 2: single block reduces the 2048 partials in double.

#define TLEN        8192
#define CPR_SHIFT   11          // chunks per row = TLEN/4 = 2048
#define CPR_MASK    2047u
#define NBLOCKS     2048
#define NTHREADS    256

__global__ __launch_bounds__(NTHREADS) void pcl_main(const float* __restrict__ x,
                                                     float* __restrict__ part_loss,
                                                     unsigned int* __restrict__ part_cnt,
                                                     int B) {
    const unsigned int total = (unsigned int)B << CPR_SHIFT;     // B * 2048 chunks
    const unsigned int gsz   = NBLOCKS * NTHREADS;
    unsigned int gid = blockIdx.x * NTHREADS + threadIdx.x;

    float loss = 0.0f;
    unsigned int cnt = 0;

    for (unsigned int c = gid; c < total; c += gsz) {
        unsigned int row = c >> CPR_SHIFT;
        unsigned int s4  = c & CPR_MASK;                          // chunk within row
        const float4* p = (const float4*)(x + ((size_t)row * TLEN + (s4 << 2)) * 3);

        float4 f0 = p[0];
        float4 f1 = p[1];
        float4 f2 = p[2];
        bool last = (s4 == CPR_MASK);                             // no successor tile
        float4 f3 = last ? make_float4(0.f, 0.f, 0.f, 0.f) : p[3];

        float v[5][3] = {
            {f0.x, f0.y, f0.z},
            {f0.w, f1.x, f1.y},
            {f1.z, f1.w, f2.x},
            {f2.y, f2.z, f2.w},
            {f3.x, f3.y, f3.z}
        };

        int   idx[5];
        float mx[5];
        #pragma unroll
        for (int k = 0; k < 5; ++k) {
            float b0 = v[k][0]; int bi = 0;
            if (v[k][1] > b0) { b0 = v[k][1]; bi = 1; }           // strict >: first-max tie-break
            if (v[k][2] > b0) { b0 = v[k][2]; bi = 2; }
            idx[k] = bi; mx[k] = b0;
        }

        int npairs = last ? 3 : 4;
        #pragma unroll
        for (int k = 0; k < 4; ++k) {
            if (k < npairs) {
                int code = idx[k] * 3 + idx[k + 1];
                if ((0xCC >> code) & 1) {
                    loss += mx[k + 1] * mx[k + 1];
                    cnt  += 1u;
                }
            }
        }
    }

    // wave-64 reduce
    #pragma unroll
    for (int off = 32; off > 0; off >>= 1) {
        loss += __shfl_down(loss, off, 64);
        cnt  += __shfl_down(cnt,  off, 64);
    }

    __shared__ float        sl[4];
    __shared__ unsigned int sc[4];
    int lane = threadIdx.x & 63;
    int wid  = threadIdx.x >> 6;
    if (lane == 0) { sl[wid] = loss; sc[wid] = cnt; }
    __syncthreads();

    if (threadIdx.x == 0) {
        part_loss[blockIdx.x] = sl[0] + sl[1] + sl[2] + sl[3];
        part_cnt[blockIdx.x]  = sc[0] + sc[1] + sc[2] + sc[3];
    }
}

__global__ __launch_bounds__(NTHREADS) void pcl_final(const float* __restrict__ part_loss,
                                                      const unsigned int* __restrict__ part_cnt,
                                                      float* __restrict__ out) {
    double L = 0.0;
    unsigned int C = 0;
    for (int i = threadIdx.x; i < NBLOCKS; i += NTHREADS) {
        L += (double)part_loss[i];
        C += part_cnt[i];
    }
    #pragma unroll
    for (int off = 32; off > 0; off >>= 1) {
        L += __shfl_down(L, off, 64);
        C += __shfl_down(C, off, 64);
    }
    __shared__ double       sl[4];
    __shared__ unsigned int sc[4];
    int lane = threadIdx.x & 63;
    int wid  = threadIdx.x >> 6;
    if (lane == 0) { sl[wid] = L; sc[wid] = C; }
    __syncthreads();
    if (threadIdx.x == 0) {
        double       Lt = sl[0] + sl[1] + sl[2] + sl[3];
        unsigned int Ct = sc[0] + sc[1] + sc[2] + sc[3];
        out[0] = (Ct > 0u) ? (float)(10.0 * Lt / (double)Ct) : 0.0f;
    }
}

extern "C" void kernel_launch(void* const* d_in, const int* in_sizes, int n_in,
                              void* d_out, int out_size, void* d_ws, size_t ws_size,
                              hipStream_t stream) {
    const float* x = (const float*)d_in[0];
    const int B = in_sizes[0] / (3 * TLEN);

    float*        part_loss = (float*)d_ws;
    unsigned int* part_cnt  = (unsigned int*)((char*)d_ws + NBLOCKS * sizeof(float));

    // Every one of the 2048 partial slots is written unconditionally by stage 1,
    // so no memset of d_ws is needed despite the 0xAA re-poison.
    pcl_main<<<NBLOCKS, NTHREADS, 0, stream>>>(x, part_loss, part_cnt, B);
    pcl_final<<<1, NTHREADS, 0, stream>>>(part_loss, part_cnt, (float*)d_out);
}